// Round 6
// baseline (505.370 us; speedup 1.0000x reference)
//
#include <hip/hip_runtime.h>
#include <hip/hip_bf16.h>

typedef __attribute__((ext_vector_type(8))) short short8;
typedef __attribute__((ext_vector_type(4))) float f32x4;

#define Bc 8
#define Tc 4096
#define Dc 1024
#define Rc 1024
#define BT (Bc*Tc)

__device__ inline float b2f(ushort u) {
    union { float f; unsigned int i; } x; x.i = ((unsigned int)u) << 16; return x.f;
}
__device__ inline ushort f2b(float f) {
    union { float f; unsigned int i; } x; x.f = f;
    unsigned int r = x.i + 0x7fffu + ((x.i >> 16) & 1u);
    return (ushort)(r >> 16);
}

__device__ inline void gload16(const void* g, void* l) {
    __builtin_amdgcn_global_load_lds(
        (const __attribute__((address_space(1))) unsigned int*)g,
        (__attribute__((address_space(3))) unsigned int*)l, 16, 0, 0);
}

// ================= 256x256 8-phase persistent-tile GEMM (C = A @ Bt^T) ======
// A: (M,K) lda bf16; Bt: (N,K) ldb bf16; tiles 256x256, BK=64, 8 waves (2Mx4N).
// LDS: 2 dbuf x (A 256x64 + B 256x64) bf16 = 128 KiB, st-swizzled.
// Persistent: grid = 1 block/CU; each block computes NTILES n-tiles sharing one
// A row-panel. The peeled last K-iteration redirects its (formerly clamped-
// redundant) stage slots to the NEXT tile's prologue loads, so the pipeline
// stays warm across tiles (per-thread vmcnt invariant preserved: 4 in flight
// at every PENDVM, buf for next reads fully landed).
// DOCS: epilogue computes per-64-row-chunk masked column sums of C into csum
//       (Kw half only, n0 >= 1024) — replaces a separate scan_partial kernel.
// EPI 0: bf16 out; EPI 1: f32 out + bias[col].

__device__ __attribute__((always_inline)) inline
short8 lds_frag(const char* mat, int rowbase, int k, int fr, int hi) {
    const int row = rowbase + fr;
    const int byte = (row << 7) + (((k << 6) + (hi << 4)) ^ ((row & 7) << 4));
    return *(const short8*)(mat + byte);
}

template<int KK>
__device__ __attribute__((always_inline)) inline
void rdb(const char* BB, short8 (&bf)[2][4], int wn, int fr, int hi) {
#pragma unroll
    for (int n = 0; n < 4; ++n)
        bf[KK][n] = lds_frag(BB, (wn << 6) + (n << 4), KK, fr, hi);
}

template<int MQ, int KK>
__device__ __attribute__((always_inline)) inline
void rda(const char* AB, short8 (&af)[4], int wm, int fr, int hi) {
#pragma unroll
    for (int i = 0; i < 4; ++i)
        af[i] = lds_frag(AB, (wm << 7) + ((MQ * 4 + i) << 4), KK, fr, hi);
}

template<int MQ, int KK>
__device__ __attribute__((always_inline)) inline
void mmq(f32x4 (&acc)[8][4], const short8 (&af)[4], const short8 (&bf)[2][4]) {
#pragma unroll
    for (int i = 0; i < 4; ++i)
#pragma unroll
        for (int n = 0; n < 4; ++n)
            acc[MQ * 4 + i][n] = __builtin_amdgcn_mfma_f32_16x16x32_bf16(
                af[i], bf[KK][n], acc[MQ * 4 + i][n], 0, 0, 0);
}

#define PH_MID do { __builtin_amdgcn_sched_barrier(0); __builtin_amdgcn_s_barrier(); \
    __builtin_amdgcn_s_setprio(1); } while (0)
#define PH_END do { __builtin_amdgcn_s_setprio(0); __builtin_amdgcn_sched_barrier(0); \
    __builtin_amdgcn_s_barrier(); } while (0)

// stage one 128-row half-tile via global_load_lds (2 per thread); linear LDS
// dest, pre-swizzled global source column group (slot ^ (row&7)).
#define STG(G, ld, thr, grow0, gk, lbase) do { \
    const ushort* _p = (G) + (size_t)(grow0) * (ld) + (gk); \
    gload16(_p + (thr), (lbase) + thrD); \
    gload16(_p + (size_t)64 * (ld) + (thr), (lbase) + thrD + 8192); } while (0)

// One K-tile: 4 phases; fragments prefetched one phase ahead.
// tnA: k-tile index for the A stage (into stA); nB/tnB: B stage target.
#define TILE2(cAb, cBb, stA, stB, tnA, nB, tnB) do { \
    /* P_a: issue bf0 + afA(k0) + afB(k0); stage A half0 */ \
    rdb<0>(cBb, bf, wn, fr, hi); \
    rda<0, 0>(cAb, afA, wm, fr, hi); \
    rda<1, 0>(cAb, afB, wm, fr, hi); \
    STG(Ab, lda, thrA, m0, (tnA) << 6, stA); \
    PH_MID; mmq<0, 0>(acc, afA, bf); PH_END; \
    /* P_b: issue bf1 + afA(k1); stage A half1 */ \
    rdb<1>(cBb, bf, wn, fr, hi); \
    rda<0, 1>(cAb, afA, wm, fr, hi); \
    STG(Ab, lda, thrA, m0 + 128, (tnA) << 6, stA + 16384); \
    PH_MID; mmq<1, 0>(acc, afB, bf); PH_END; \
    /* P_c: issue afB(k1) */ \
    rda<1, 1>(cAb, afB, wm, fr, hi); \
    PH_MID; mmq<0, 1>(acc, afA, bf); PH_END; \
    /* P_d: stage B halves (own-buf B dead after P_c end barrier) */ \
    STG(Bt, ldb, thrB, (nB),       (tnB) << 6, stB); \
    STG(Bt, ldb, thrB, (nB) + 128, (tnB) << 6, stB + 16384); \
    PH_MID; mmq<1, 1>(acc, afB, bf); \
    __builtin_amdgcn_s_setprio(0); __builtin_amdgcn_sched_barrier(0); \
    asm volatile("s_waitcnt vmcnt(4)" ::: "memory"); \
    __builtin_amdgcn_s_barrier(); } while (0)

template<int EPI, int DOCS, int NTILES>
__global__ __launch_bounds__(512, 2)
void gemm256(const ushort* __restrict__ Ab, const ushort* __restrict__ Bt,
             void* __restrict__ Cout, const float* __restrict__ bias,
             const float* __restrict__ maskf, float* __restrict__ csum,
             int ntx, int K, int lda, int ldb, int ldc) {
    __shared__ __align__(16) char sA[65536];
    __shared__ __align__(16) char sB[65536];

    const int tid = threadIdx.x;
    const int w = tid >> 6, l = tid & 63;
    const int wm = w >> 2, wn = w & 3;
    const int fr = l & 15, hi = l >> 4;
    const int srow = (w << 3) + (l >> 3);
    const int scg = (((l & 7) ^ (l >> 3)) << 3);
    const size_t thrA = (size_t)srow * lda + scg;
    const size_t thrB = (size_t)srow * ldb + scg;
    const int thrD = (w << 10) + (l << 4);

    // bijective XCD swizzle (gridDim.x % 8 == 0)
    const int nwg = (int)gridDim.x;
    const int q = nwg >> 3;
    const int bid = (int)blockIdx.x;
    const int swz = (bid & 7) * q + (bid >> 3);
    const int xpb = ntx / NTILES;            // blocks per A row-panel
    const int by = swz / xpb, sub = swz % xpb;
    const int m0 = by << 8;

    f32x4 acc[8][4];
    short8 afA[4], afB[4], bf[2][4];
    const int NT = K >> 6;                   // K-tiles (16 here), even

    const char* cA0 = sA;
    const char* cB0 = sB;
    const char* cA1 = sA + 32768;
    const char* cB1 = sB + 32768;

    int n0 = (sub * NTILES) << 8;

    // ---- cold prologue (tile 0 only): buf0 full @ t0, buf1 B halves @ t1 ----
    STG(Ab, lda, thrA, m0,        0,  sA);
    STG(Ab, lda, thrA, m0 + 128,  0,  sA + 16384);
    STG(Bt, ldb, thrB, n0,        0,  sB);
    STG(Bt, ldb, thrB, n0 + 128,  0,  sB + 16384);
    STG(Bt, ldb, thrB, n0,        64, sB + 32768);
    STG(Bt, ldb, thrB, n0 + 128,  64, sB + 32768 + 16384);
    asm volatile("s_waitcnt vmcnt(4)" ::: "memory");
    __builtin_amdgcn_sched_barrier(0);
    __builtin_amdgcn_s_barrier();

    for (int tt = 0; tt < NTILES; ++tt) {
        const int n0n = (tt + 1 < NTILES) ? n0 + 256 : n0;  // next tile (or self)

#pragma unroll
        for (int m = 0; m < 8; ++m)
#pragma unroll
            for (int n = 0; n < 4; ++n)
                acc[m][n] = (f32x4){0.f, 0.f, 0.f, 0.f};

        // normal iterations: no clamping needed (t3 <= NT-1)
        for (int it = 0; it < (NT >> 1) - 1; ++it) {
            const int t1 = 2 * it + 1, t2 = 2 * it + 2, t3 = 2 * it + 3;
            TILE2(cA0, cB0, sA + 32768, sB,         t1, n0, t2);
            TILE2(cA1, cB1, sA,         sB + 32768, t2, n0, t3);
        }
        // peeled last iteration: redirect stage slots to next tile's prologue
        TILE2(cA0, cB0, sA + 32768, sB,         NT - 1, n0n, 0);
        TILE2(cA1, cB1, sA,         sB + 32768, 0,      n0n, 1);

        // ---- epilogue: C write (covers latency of the 4 in-flight loads) ----
        const int crow = m0 + (wm << 7);
        const int ccol = n0 + (wn << 6);
#pragma unroll
        for (int m = 0; m < 8; ++m) {
#pragma unroll
            for (int n = 0; n < 4; ++n) {
                const int r0 = crow + (m << 4) + (hi << 2);
                const int c = ccol + (n << 4) + fr;
                if (EPI == 0) {
                    ushort* C = (ushort*)Cout;
#pragma unroll
                    for (int t = 0; t < 4; ++t)
                        C[(size_t)(r0 + t) * ldc + c] = f2b(acc[m][n][t]);
                } else {
                    float* C = (float*)Cout;
                    const float bv = bias[c];
#pragma unroll
                    for (int t = 0; t < 4; ++t)
                        C[(size_t)(r0 + t) * ldc + c] = acc[m][n][t] + bv;
                }
            }
        }

        // ---- epilogue: fused per-chunk masked column sums (Kw half only) ----
        if (DOCS && n0 >= 1024) {
            const float* mrow = maskf + crow;
#pragma unroll
            for (int mh = 0; mh < 2; ++mh) {
                float cs0 = 0.f, cs1 = 0.f, cs2 = 0.f, cs3 = 0.f;
#pragma unroll
                for (int mm = 0; mm < 4; ++mm) {
                    const int m = mh * 4 + mm;
                    const float4 mk = *(const float4*)(mrow + (m << 4) + (hi << 2));
                    cs0 += acc[m][0][0] * mk.x + acc[m][0][1] * mk.y + acc[m][0][2] * mk.z + acc[m][0][3] * mk.w;
                    cs1 += acc[m][1][0] * mk.x + acc[m][1][1] * mk.y + acc[m][1][2] * mk.z + acc[m][1][3] * mk.w;
                    cs2 += acc[m][2][0] * mk.x + acc[m][2][1] * mk.y + acc[m][2][2] * mk.z + acc[m][2][3] * mk.w;
                    cs3 += acc[m][3][0] * mk.x + acc[m][3][1] * mk.y + acc[m][3][2] * mk.z + acc[m][3][3] * mk.w;
                }
                float cs[4] = {cs0, cs1, cs2, cs3};
                const int g = (crow + (mh << 6)) >> 6;   // global 64-row chunk
#pragma unroll
                for (int n = 0; n < 4; ++n) {
                    float v = cs[n];
                    v += __shfl_xor(v, 16, 64);
                    v += __shfl_xor(v, 32, 64);
                    if (hi == 0) {
                        const int r = (ccol - 1024) + (n << 4) + fr;
                        csum[(size_t)g * 1024 + r] = v;
                    }
                }
            }
        }

        n0 = n0n;
    }
}

// ---------------- cast f32 -> bf16 (vectorized) ----------------
__global__ void cast_f32_bf16(const float4* __restrict__ in, ushort4* __restrict__ out, int n4) {
    int i = blockIdx.x * blockDim.x + threadIdx.x;
    int stride = gridDim.x * blockDim.x;
    for (; i < n4; i += stride) {
        float4 v = in[i];
        ushort4 o;
        o.x = f2b(v.x); o.y = f2b(v.y); o.z = f2b(v.z); o.w = f2b(v.w);
        out[i] = o;
    }
}

// ---------------- weight prep: 5 transposes + 1 plain cast, one launch ------
__global__ void prep_weights(const float* __restrict__ V,  const float* __restrict__ Wb,
                             const float* __restrict__ U,  const float* __restrict__ WQ,
                             const float* __restrict__ WK, const float* __restrict__ WO,
                             ushort* __restrict__ Vt,  ushort* __restrict__ Wbt,
                             ushort* __restrict__ Ut,  ushort* __restrict__ WQt,
                             ushort* __restrict__ WKt, ushort* __restrict__ WOb) {
    __shared__ float tile[32][33];
    const float* in; ushort* out;
    switch (blockIdx.z) {
        case 0: in = V;  out = Vt;  break;
        case 1: in = Wb; out = Wbt; break;
        case 2: in = U;  out = Ut;  break;
        case 3: in = WQ; out = WQt; break;
        case 4: in = WK; out = WKt; break;
        default: in = WO; out = WOb; break;
    }
    int c0 = blockIdx.x * 32, r0 = blockIdx.y * 32;
    int tx = threadIdx.x & 31, ty = threadIdx.x >> 5; // 32 x 8
    if (blockIdx.z < 5) {
        for (int i = 0; i < 32; i += 8)
            tile[ty + i][tx] = in[(size_t)(r0 + ty + i) * 1024 + c0 + tx];
        __syncthreads();
        for (int i = 0; i < 32; i += 8)
            out[(size_t)(c0 + ty + i) * 1024 + r0 + tx] = f2b(tile[tx][ty + i]);
    } else {
        for (int i = 0; i < 32; i += 8)
            out[(size_t)(r0 + ty + i) * 1024 + c0 + tx] =
                f2b(in[(size_t)(r0 + ty + i) * 1024 + c0 + tx]);
    }
}

// ---------------- batched small 128x128 GEMM (3 weight products) ------------
__global__ __launch_bounds__(256)
void gemm_bt3(const ushort* __restrict__ Vt,  const ushort* __restrict__ WQt,
              const ushort* __restrict__ Wbt, const ushort* __restrict__ WKt,
              const ushort* __restrict__ WOb, const ushort* __restrict__ Ut,
              ushort* __restrict__ W1, ushort* __restrict__ Mmat) {
    const ushort *A, *Bt; ushort* Cout;
    switch (blockIdx.z) {
        case 0: A = Vt;  Bt = WQt; Cout = W1; break;
        case 1: A = Wbt; Bt = WKt; Cout = W1 + (size_t)Rc * Dc; break;
        default: A = WOb; Bt = Ut; Cout = Mmat; break;
    }
    __shared__ __align__(16) ushort As[128][32];
    __shared__ __align__(16) ushort Bs[128][32];
    const int tid = threadIdx.x;
    const int wave = tid >> 6, lane = tid & 63;
    const int m0 = blockIdx.y * 128, n0 = blockIdx.x * 128;
    const int wr = (wave >> 1) * 64, wc = (wave & 1) * 64;

    f32x4 acc[4][4] = {};

    const int rS = wave * 32 + (lane >> 2);
    const int kS = (lane & 3) * 8;
    const int fr = lane & 15;
    const int fq = (lane >> 4) * 8;

    for (int kt = 0; kt < 32; ++kt) {
        const int k0 = kt << 5;
        __syncthreads();
        gload16(A  + (size_t)(m0 + rS) * 1024      + k0 + kS, &As[rS][kS]);
        gload16(A  + (size_t)(m0 + rS + 16) * 1024 + k0 + kS, &As[rS + 16][kS]);
        gload16(Bt + (size_t)(n0 + rS) * 1024      + k0 + kS, &Bs[rS][kS]);
        gload16(Bt + (size_t)(n0 + rS + 16) * 1024 + k0 + kS, &Bs[rS + 16][kS]);
        __syncthreads();

        short8 af[4], bfr[4];
        #pragma unroll
        for (int i = 0; i < 4; i++) af[i]  = *(const short8*)&As[wr + i * 16 + fr][fq];
        #pragma unroll
        for (int i = 0; i < 4; i++) bfr[i] = *(const short8*)&Bs[wc + i * 16 + fr][fq];
        #pragma unroll
        for (int i = 0; i < 4; i++)
            #pragma unroll
            for (int j = 0; j < 4; j++)
                acc[i][j] = __builtin_amdgcn_mfma_f32_16x16x32_bf16(af[i], bfr[j], acc[i][j], 0, 0, 0);
    }

    const int rq = (lane >> 4) * 4;
    #pragma unroll
    for (int i = 0; i < 4; i++) {
        #pragma unroll
        for (int j = 0; j < 4; j++) {
            int row = m0 + wr + i * 16 + rq;
            int col = n0 + wc + j * 16 + fr;
            #pragma unroll
            for (int t = 0; t < 4; t++)
                Cout[(size_t)(row + t) * 1024 + col] = f2b(acc[i][j][t]);
        }
    }
}

// ---------------- biasO[e] = sum_d W_O[e][d] * bias[d] ----------------
__global__ void bias_O_kernel(const float* __restrict__ W_O, const float* __restrict__ bias,
                              float* __restrict__ biasO) {
    __shared__ float sh[256];
    int e = blockIdx.x, tid = threadIdx.x;
    float s = 0.f;
    for (int d = tid; d < Dc; d += 256) s += W_O[(size_t)e * Dc + d] * bias[d];
    sh[tid] = s; __syncthreads();
    for (int o = 128; o > 0; o >>= 1) { if (tid < o) sh[tid] += sh[tid + o]; __syncthreads(); }
    if (tid == 0) biasO[e] = sh[0];
}

// ------------- mask scan: n[b][t] = cumsum(mask); maskf = (float)mask -------
__global__ void mask_scan(const int* __restrict__ mask, float* __restrict__ nbuf,
                          float* __restrict__ maskf) {
    __shared__ float sh[256];
    int b = blockIdx.x, tid = threadIdx.x;
    float run = 0.f;
    for (int t0 = 0; t0 < Tc; t0 += 256) {
        float v = (mask[b * Tc + t0 + tid] != 0) ? 1.f : 0.f;
        maskf[b * Tc + t0 + tid] = v;
        sh[tid] = v; __syncthreads();
        for (int off = 1; off < 256; off <<= 1) {
            float add = (tid >= off) ? sh[tid - off] : 0.f;
            __syncthreads();
            sh[tid] += add;
            __syncthreads();
        }
        nbuf[b * Tc + t0 + tid] = run + sh[tid];
        run += sh[255];
        __syncthreads();
    }
}

// ---------------- scan_apply: prefix over chunks + P = A*S/max(n,1) ---------
#define NCHUNK 64
#define LCHUNK (Tc / NCHUNK)   // 64

__global__ void scan_apply(ushort* __restrict__ AKw, const int* __restrict__ mask,
                           const float* __restrict__ csum, const float* __restrict__ nbuf) {
    const int r = threadIdx.x * 4;
    const int chunk = blockIdx.x, b = blockIdx.y;
    const int row0 = b * Tc + chunk * LCHUNK;
    // exclusive prefix over preceding chunks (csum holds raw per-chunk sums)
    float4 s = {0.f, 0.f, 0.f, 0.f};
    for (int c = 0; c < chunk; ++c) {
        float4 v = *(const float4*)(csum + (((size_t)b * NCHUNK + c) << 10) + r);
        s.x += v.x; s.y += v.y; s.z += v.z; s.w += v.w;
    }
    ushort* p = AKw + (size_t)row0 * 2048 + r;
    for (int t = 0; t < LCHUNK; ++t) {
        const size_t off = (size_t)t * 2048;
        if (mask[row0 + t] != 0) {
            ushort4 kw = *(const ushort4*)(p + off + 1024);
            s.x += b2f(kw.x); s.y += b2f(kw.y); s.z += b2f(kw.z); s.w += b2f(kw.w);
        }
        const float rn = 1.f / fmaxf(nbuf[row0 + t], 1.f);
        ushort4 a = *(const ushort4*)(p + off);
        ushort4 o;
        o.x = f2b(b2f(a.x) * s.x * rn);
        o.y = f2b(b2f(a.y) * s.y * rn);
        o.z = f2b(b2f(a.z) * s.z * rn);
        o.w = f2b(b2f(a.w) * s.w * rn);
        *(ushort4*)(p + off) = o;
    }
}

extern "C" void kernel_launch(void* const* d_in, const int* in_sizes, int n_in,
                              void* d_out, int out_size, void* d_ws, size_t ws_size,
                              hipStream_t stream) {
    const float* x    = (const float*)d_in[0];
    const int*   mask = (const int*)d_in[1];
    const float* W_Q  = (const float*)d_in[2];
    const float* W_K  = (const float*)d_in[3];
    const float* U    = (const float*)d_in[4];
    const float* V    = (const float*)d_in[5];
    const float* Wb   = (const float*)d_in[6];
    const float* bias = (const float*)d_in[7];
    const float* W_O  = (const float*)d_in[8];
    float* out = (float*)d_out;

    char* ws = (char*)d_ws;
    ushort* xb   = (ushort*)ws; ws += (size_t)BT * Dc * 2;            // 67 MB
    ushort* AKw  = (ushort*)ws; ws += (size_t)BT * 2048 * 2;          // 134 MB
    ushort* W1   = (ushort*)ws; ws += (size_t)2048 * Dc * 2;          // 4 MB
    ushort* Mmat = (ushort*)ws; ws += (size_t)Dc * Rc * 2;            // 2 MB
    ushort* Vt   = (ushort*)ws; ws += (size_t)Dc * Rc * 2;
    ushort* Wbt  = (ushort*)ws; ws += (size_t)Dc * Rc * 2;
    ushort* Ut   = (ushort*)ws; ws += (size_t)Dc * Rc * 2;
    ushort* WQt  = (ushort*)ws; ws += (size_t)Dc * Dc * 2;
    ushort* WKt  = (ushort*)ws; ws += (size_t)Dc * Dc * 2;
    ushort* WOb  = (ushort*)ws; ws += (size_t)Dc * Dc * 2;
    float*  csum = (float*)ws;  ws += (size_t)Bc * NCHUNK * Rc * 4;   // 2 MB
    float*  nbuf = (float*)ws;  ws += (size_t)Bc * Tc * 4;
    float*  maskf= (float*)ws;  ws += (size_t)Bc * Tc * 4;
    float*  biasO = (float*)ws; ws += (size_t)Dc * 4;

    // 1. cast x, weight prep, mask scan (maskf needed by GEMM1 epilogue)
    cast_f32_bf16<<<2048, 256, 0, stream>>>((const float4*)x, (ushort4*)xb, BT * Dc / 4);
    prep_weights<<<dim3(32, 32, 6), 256, 0, stream>>>(V, Wb, U, W_Q, W_K, W_O,
                                                      Vt, Wbt, Ut, WQt, WKt, WOb);
    mask_scan<<<Bc, 256, 0, stream>>>(mask, nbuf, maskf);

    // 2. fused weights (batched) + biasO
    gemm_bt3<<<dim3(8, 8, 3), 256, 0, stream>>>(Vt, WQt, Wbt, WKt, WOb, Ut, W1, Mmat);
    bias_O_kernel<<<Dc, 256, 0, stream>>>(W_O, bias, biasO);

    // 3. AKw = xb @ W1^T (M=32768, N=2048, K=1024), bf16 out, persistent 4
    //    n-tiles/block; epilogue writes csum raw per-chunk masked column sums
    gemm256<0, 1, 4><<<256, 512, 0, stream>>>(xb, W1, AKw, nullptr, maskf, csum,
                                              8, Dc, Dc, Dc, 2048);

    // 4. scan_apply: per-block prefix over csum chunks, P = A*S/max(n,1) in place
    scan_apply<<<dim3(NCHUNK, Bc), 256, 0, stream>>>(AKw, mask, csum, nbuf);

    // 5. out = P @ Mmat^T + biasO (M=32768, N=1024, K=1024), f32 out, persistent 2
    gemm256<1, 0, 2><<<256, 512, 0, stream>>>(AKw, Mmat, out, biasO, nullptr, nullptr,
                                              4, Rc, 2048, Rc, Dc);
}

// Round 7
// 379.692 us; speedup vs baseline: 1.3310x; 1.3310x over previous
//
#include <hip/hip_runtime.h>
#include <hip/hip_bf16.h>

typedef __attribute__((ext_vector_type(8))) short short8;
typedef __attribute__((ext_vector_type(4))) float f32x4;

#define Bc 8
#define Tc 4096
#define Dc 1024
#define Rc 1024
#define BT (Bc*Tc)

__device__ inline float b2f(ushort u) {
    union { float f; unsigned int i; } x; x.i = ((unsigned int)u) << 16; return x.f;
}
__device__ inline ushort f2b(float f) {
    union { float f; unsigned int i; } x; x.f = f;
    unsigned int r = x.i + 0x7fffu + ((x.i >> 16) & 1u);
    return (ushort)(r >> 16);
}

__device__ inline void gload16(const void* g, void* l) {
    __builtin_amdgcn_global_load_lds(
        (const __attribute__((address_space(1))) unsigned int*)g,
        (__attribute__((address_space(3))) unsigned int*)l, 16, 0, 0);
}

// ================= 256x256 8-phase GEMM (C = A @ Bt^T) =================
// R5-proven form (non-persistent). A: (M,K) lda bf16; Bt: (N,K) ldb bf16;
// tiles 256x256, BK=64, 8 waves (2Mx4N); LDS 2dbuf x (A+B 256x64) = 128 KiB,
// st-swizzled via pre-swizzled global source + swizzled ds_read (rule 21).
// R4 lesson: do NOT reg-stage A from f32 (exposes HBM latency at 1 wg/CU).
// R6 lesson: do NOT persist across n-tiles (A panel falls out of L2, FETCH 3x).
// DOCS: epilogue computes per-64-row-chunk masked column sums of C into csum
//       (Kw half only, n0 >= 1024) — replaces a separate scan_partial kernel.
// EPI 0: bf16 out; EPI 1: f32 out + bias[col].

__device__ __attribute__((always_inline)) inline
short8 lds_frag(const char* mat, int rowbase, int k, int fr, int hi) {
    const int row = rowbase + fr;
    const int byte = (row << 7) + (((k << 6) + (hi << 4)) ^ ((row & 7) << 4));
    return *(const short8*)(mat + byte);
}

template<int KK>
__device__ __attribute__((always_inline)) inline
void rdb(const char* BB, short8 (&bf)[2][4], int wn, int fr, int hi) {
#pragma unroll
    for (int n = 0; n < 4; ++n)
        bf[KK][n] = lds_frag(BB, (wn << 6) + (n << 4), KK, fr, hi);
}

template<int MQ, int KK>
__device__ __attribute__((always_inline)) inline
void rda(const char* AB, short8 (&af)[4], int wm, int fr, int hi) {
#pragma unroll
    for (int i = 0; i < 4; ++i)
        af[i] = lds_frag(AB, (wm << 7) + ((MQ * 4 + i) << 4), KK, fr, hi);
}

template<int MQ, int KK>
__device__ __attribute__((always_inline)) inline
void mmq(f32x4 (&acc)[8][4], const short8 (&af)[4], const short8 (&bf)[2][4]) {
#pragma unroll
    for (int i = 0; i < 4; ++i)
#pragma unroll
        for (int n = 0; n < 4; ++n)
            acc[MQ * 4 + i][n] = __builtin_amdgcn_mfma_f32_16x16x32_bf16(
                af[i], bf[KK][n], acc[MQ * 4 + i][n], 0, 0, 0);
}

#define PH_MID do { __builtin_amdgcn_sched_barrier(0); __builtin_amdgcn_s_barrier(); \
    __builtin_amdgcn_s_setprio(1); } while (0)
#define PH_END do { __builtin_amdgcn_s_setprio(0); __builtin_amdgcn_sched_barrier(0); \
    __builtin_amdgcn_s_barrier(); } while (0)

// stage one 128-row half-tile via global_load_lds (2 per thread); linear LDS
// dest, pre-swizzled global source column group (slot ^ (row&7)).
#define STG(G, ld, thr, grow0, gk, lbase) do { \
    const ushort* _p = (G) + (size_t)(grow0) * (ld) + (gk); \
    gload16(_p + (thr), (lbase) + thrD); \
    gload16(_p + (size_t)64 * (ld) + (thr), (lbase) + thrD + 8192); } while (0)

// One K-tile: 4 phases; fragments prefetched one phase ahead.
#define TILE(cAb, cBb, stA, stB, tn, tn2) do { \
    /* P_a: issue bf0 + afA(k0) + afB(k0); stage other-buf A half0 @ tn */ \
    rdb<0>(cBb, bf, wn, fr, hi); \
    rda<0, 0>(cAb, afA, wm, fr, hi); \
    rda<1, 0>(cAb, afB, wm, fr, hi); \
    STG(Ab, lda, thrA, m0, (tn) << 6, stA); \
    PH_MID; mmq<0, 0>(acc, afA, bf); PH_END; \
    /* P_b: issue bf1 + afA(k1); stage other-buf A half1 @ tn */ \
    rdb<1>(cBb, bf, wn, fr, hi); \
    rda<0, 1>(cAb, afA, wm, fr, hi); \
    STG(Ab, lda, thrA, m0 + 128, (tn) << 6, stA + 16384); \
    PH_MID; mmq<1, 0>(acc, afB, bf); PH_END; \
    /* P_c: issue afB(k1) */ \
    rda<1, 1>(cAb, afB, wm, fr, hi); \
    PH_MID; mmq<0, 1>(acc, afA, bf); PH_END; \
    /* P_d: stage own-buf B halves @ tn2 (own B dead after P_c end barrier) */ \
    STG(Bt, ldb, thrB, n0,       (tn2) << 6, stB); \
    STG(Bt, ldb, thrB, n0 + 128, (tn2) << 6, stB + 16384); \
    PH_MID; mmq<1, 1>(acc, afB, bf); \
    __builtin_amdgcn_s_setprio(0); __builtin_amdgcn_sched_barrier(0); \
    asm volatile("s_waitcnt vmcnt(4)" ::: "memory"); \
    __builtin_amdgcn_s_barrier(); } while (0)

template<int EPI, int DOCS>
__global__ __launch_bounds__(512, 2)
void gemm256(const ushort* __restrict__ Ab, const ushort* __restrict__ Bt,
             void* __restrict__ Cout, const float* __restrict__ bias,
             const float* __restrict__ maskf, float* __restrict__ csum,
             int ntx, int K, int lda, int ldb, int ldc) {
    __shared__ __align__(16) char sA[65536];
    __shared__ __align__(16) char sB[65536];

    const int tid = threadIdx.x;
    const int w = tid >> 6, l = tid & 63;
    const int wm = w >> 2, wn = w & 3;
    const int fr = l & 15, hi = l >> 4;
    const int srow = (w << 3) + (l >> 3);
    const int scg = (((l & 7) ^ (l >> 3)) << 3);
    const size_t thrA = (size_t)srow * lda + scg;
    const size_t thrB = (size_t)srow * ldb + scg;
    const int thrD = (w << 10) + (l << 4);

    // bijective XCD swizzle (gridDim.x % 8 == 0), row-major chunk per XCD
    const int nwg = (int)gridDim.x;
    const int q = nwg >> 3;
    const int bid = (int)blockIdx.x;
    const int swz = (bid & 7) * q + (bid >> 3);
    const int by = swz / ntx, bx = swz % ntx;
    const int m0 = by << 8, n0 = bx << 8;

    f32x4 acc[8][4] = {};
    short8 afA[4], afB[4], bf[2][4];
    const int NT = K >> 6;

    // ---- prologue: buf0 full @ t0, buf1 B halves @ t1 ----
    STG(Ab, lda, thrA, m0,        0,  sA);
    STG(Ab, lda, thrA, m0 + 128,  0,  sA + 16384);
    STG(Bt, ldb, thrB, n0,        0,  sB);
    STG(Bt, ldb, thrB, n0 + 128,  0,  sB + 16384);
    STG(Bt, ldb, thrB, n0,        64, sB + 32768);
    STG(Bt, ldb, thrB, n0 + 128,  64, sB + 32768 + 16384);
    asm volatile("s_waitcnt vmcnt(4)" ::: "memory");
    __builtin_amdgcn_sched_barrier(0);
    __builtin_amdgcn_s_barrier();

    const char* cA0 = sA;
    const char* cB0 = sB;
    const char* cA1 = sA + 32768;
    const char* cB1 = sB + 32768;

    for (int it = 0; it < (NT >> 1); ++it) {
        const int t1 = 2 * it + 1;
        const int t2 = min(2 * it + 2, NT - 1);
        const int t3 = min(2 * it + 3, NT - 1);
        // tile 2it on buf0: stage buf1.A@t1, buf0.B@t2
        TILE(cA0, cB0, sA + 32768, sB, t1, t2);
        // tile 2it+1 on buf1: stage buf0.A@t2, buf1.B@t3
        TILE(cA1, cB1, sA, sB + 32768, t2, t3);
    }

    // ---- epilogue: C write ----
    const int crow = m0 + (wm << 7);
    const int ccol = n0 + (wn << 6);
#pragma unroll
    for (int m = 0; m < 8; ++m) {
#pragma unroll
        for (int n = 0; n < 4; ++n) {
            const int r0 = crow + (m << 4) + (hi << 2);
            const int c = ccol + (n << 4) + fr;
            if (EPI == 0) {
                ushort* C = (ushort*)Cout;
#pragma unroll
                for (int t = 0; t < 4; ++t)
                    C[(size_t)(r0 + t) * ldc + c] = f2b(acc[m][n][t]);
            } else {
                float* C = (float*)Cout;
                const float bv = bias[c];
#pragma unroll
                for (int t = 0; t < 4; ++t)
                    C[(size_t)(r0 + t) * ldc + c] = acc[m][n][t] + bv;
            }
        }
    }

    // ---- epilogue: fused per-chunk masked column sums (Kw half only) ----
    if (DOCS && n0 >= 1024) {
        const float* mrow = maskf + crow;
#pragma unroll
        for (int mh = 0; mh < 2; ++mh) {
            float cs0 = 0.f, cs1 = 0.f, cs2 = 0.f, cs3 = 0.f;
#pragma unroll
            for (int mm = 0; mm < 4; ++mm) {
                const int m = mh * 4 + mm;
                const float4 mk = *(const float4*)(mrow + (m << 4) + (hi << 2));
                cs0 += acc[m][0][0] * mk.x + acc[m][0][1] * mk.y + acc[m][0][2] * mk.z + acc[m][0][3] * mk.w;
                cs1 += acc[m][1][0] * mk.x + acc[m][1][1] * mk.y + acc[m][1][2] * mk.z + acc[m][1][3] * mk.w;
                cs2 += acc[m][2][0] * mk.x + acc[m][2][1] * mk.y + acc[m][2][2] * mk.z + acc[m][2][3] * mk.w;
                cs3 += acc[m][3][0] * mk.x + acc[m][3][1] * mk.y + acc[m][3][2] * mk.z + acc[m][3][3] * mk.w;
            }
            float cs[4] = {cs0, cs1, cs2, cs3};
            const int g = (crow + (mh << 6)) >> 6;   // global 64-row chunk index
#pragma unroll
            for (int n = 0; n < 4; ++n) {
                float v = cs[n];
                v += __shfl_xor(v, 16, 64);
                v += __shfl_xor(v, 32, 64);
                if (hi == 0) {
                    const int r = (ccol - 1024) + (n << 4) + fr;
                    csum[(size_t)g * 1024 + r] = v;
                }
            }
        }
    }
}

// ======== fused prologue: cast x, 5 transposes, WO cast, mask scan ==========
// grid layout (1D, 256 threads/block):
//   [0, 2048)        : cast x -> xb (grid-stride over float4s)
//   [2048, 8192)     : weight prep, z = (bid-2048)>>10 in 0..5 (5 transposes + WO cast)
//   [8192, 8200)     : mask scan, b = bid - 8192
__global__ void fused_prep(const float* __restrict__ x, ushort* __restrict__ xb,
                           const int* __restrict__ mask, float* __restrict__ nbuf,
                           float* __restrict__ maskf,
                           const float* __restrict__ V,  const float* __restrict__ Wb,
                           const float* __restrict__ U,  const float* __restrict__ WQ,
                           const float* __restrict__ WK, const float* __restrict__ WO,
                           ushort* __restrict__ Vt,  ushort* __restrict__ Wbt,
                           ushort* __restrict__ Ut,  ushort* __restrict__ WQt,
                           ushort* __restrict__ WKt, ushort* __restrict__ WOb) {
    __shared__ float sh[32 * 33];
    const int bid = blockIdx.x, tid = threadIdx.x;

    if (bid < 2048) {
        // ---- cast x -> bf16 ----
        const float4* in = (const float4*)x;
        ushort4* out = (ushort4*)xb;
        const int n4 = BT * Dc / 4;
        for (int i = bid * 256 + tid; i < n4; i += 2048 * 256) {
            float4 v = in[i];
            ushort4 o;
            o.x = f2b(v.x); o.y = f2b(v.y); o.z = f2b(v.z); o.w = f2b(v.w);
            out[i] = o;
        }
    } else if (bid < 8192) {
        // ---- weight prep ----
        const int zz = (bid - 2048) >> 10;
        const int rem = (bid - 2048) & 1023;
        const int c0 = (rem & 31) * 32, r0 = (rem >> 5) * 32;
        const float* in; ushort* out;
        switch (zz) {
            case 0: in = V;  out = Vt;  break;
            case 1: in = Wb; out = Wbt; break;
            case 2: in = U;  out = Ut;  break;
            case 3: in = WQ; out = WQt; break;
            case 4: in = WK; out = WKt; break;
            default: in = WO; out = WOb; break;
        }
        const int tx = tid & 31, ty = tid >> 5; // 32 x 8
        if (zz < 5) {
            for (int i = 0; i < 32; i += 8)
                sh[(ty + i) * 33 + tx] = in[(size_t)(r0 + ty + i) * 1024 + c0 + tx];
            __syncthreads();
            for (int i = 0; i < 32; i += 8)
                out[(size_t)(c0 + ty + i) * 1024 + r0 + tx] = f2b(sh[tx * 33 + ty + i]);
        } else {
            for (int i = 0; i < 32; i += 8)
                out[(size_t)(r0 + ty + i) * 1024 + c0 + tx] =
                    f2b(in[(size_t)(r0 + ty + i) * 1024 + c0 + tx]);
        }
    } else {
        // ---- mask scan: nbuf = cumsum(mask), maskf = (float)mask ----
        const int b = bid - 8192;
        float run = 0.f;
        for (int t0 = 0; t0 < Tc; t0 += 256) {
            float v = (mask[b * Tc + t0 + tid] != 0) ? 1.f : 0.f;
            maskf[b * Tc + t0 + tid] = v;
            sh[tid] = v; __syncthreads();
            for (int off = 1; off < 256; off <<= 1) {
                float add = (tid >= off) ? sh[tid - off] : 0.f;
                __syncthreads();
                sh[tid] += add;
                __syncthreads();
            }
            nbuf[b * Tc + t0 + tid] = run + sh[tid];
            run += sh[255];
            __syncthreads();
        }
    }
}

// ------- batched small 128x128 GEMM (3 weight products) + biasO (z=3) -------
__global__ __launch_bounds__(256)
void gemm_bt3b(const ushort* __restrict__ Vt,  const ushort* __restrict__ WQt,
               const ushort* __restrict__ Wbt, const ushort* __restrict__ WKt,
               const ushort* __restrict__ WOb, const ushort* __restrict__ Ut,
               ushort* __restrict__ W1, ushort* __restrict__ Mmat,
               const float* __restrict__ WO_f, const float* __restrict__ bias,
               float* __restrict__ biasO) {
    const int tid = threadIdx.x;
    if (blockIdx.z == 3) {
        // biasO[e] = sum_d W_O[e][d] * bias[d]; 64 blocks x 16 e each,
        // 16 threads per e (64-elem strips), shfl-reduce within 16-group.
        const int e = (blockIdx.y * 8 + blockIdx.x) * 16 + (tid >> 4);
        const int d0 = (tid & 15) * 64;
        float s = 0.f;
        for (int d = d0; d < d0 + 64; ++d)
            s += WO_f[(size_t)e * Dc + d] * bias[d];
        s += __shfl_xor(s, 1, 64); s += __shfl_xor(s, 2, 64);
        s += __shfl_xor(s, 4, 64); s += __shfl_xor(s, 8, 64);
        if ((tid & 15) == 0) biasO[e] = s;
        return;
    }
    const ushort *A, *Bt; ushort* Cout;
    switch (blockIdx.z) {
        case 0: A = Vt;  Bt = WQt; Cout = W1; break;
        case 1: A = Wbt; Bt = WKt; Cout = W1 + (size_t)Rc * Dc; break;
        default: A = WOb; Bt = Ut; Cout = Mmat; break;
    }
    __shared__ __align__(16) ushort As[128][32];
    __shared__ __align__(16) ushort Bs[128][32];
    const int wave = tid >> 6, lane = tid & 63;
    const int m0 = blockIdx.y * 128, n0 = blockIdx.x * 128;
    const int wr = (wave >> 1) * 64, wc = (wave & 1) * 64;

    f32x4 acc[4][4] = {};

    const int rS = wave * 32 + (lane >> 2);
    const int kS = (lane & 3) * 8;
    const int fr = lane & 15;
    const int fq = (lane >> 4) * 8;

    for (int kt = 0; kt < 32; ++kt) {
        const int k0 = kt << 5;
        __syncthreads();
        gload16(A  + (size_t)(m0 + rS) * 1024      + k0 + kS, &As[rS][kS]);
        gload16(A  + (size_t)(m0 + rS + 16) * 1024 + k0 + kS, &As[rS + 16][kS]);
        gload16(Bt + (size_t)(n0 + rS) * 1024      + k0 + kS, &Bs[rS][kS]);
        gload16(Bt + (size_t)(n0 + rS + 16) * 1024 + k0 + kS, &Bs[rS + 16][kS]);
        __syncthreads();

        short8 af[4], bfr[4];
        #pragma unroll
        for (int i = 0; i < 4; i++) af[i]  = *(const short8*)&As[wr + i * 16 + fr][fq];
        #pragma unroll
        for (int i = 0; i < 4; i++) bfr[i] = *(const short8*)&Bs[wc + i * 16 + fr][fq];
        #pragma unroll
        for (int i = 0; i < 4; i++)
            #pragma unroll
            for (int j = 0; j < 4; j++)
                acc[i][j] = __builtin_amdgcn_mfma_f32_16x16x32_bf16(af[i], bfr[j], acc[i][j], 0, 0, 0);
    }

    const int rq = (lane >> 4) * 4;
    #pragma unroll
    for (int i = 0; i < 4; i++) {
        #pragma unroll
        for (int j = 0; j < 4; j++) {
            int row = m0 + wr + i * 16 + rq;
            int col = n0 + wc + j * 16 + fr;
            #pragma unroll
            for (int t = 0; t < 4; t++)
                Cout[(size_t)(row + t) * 1024 + col] = f2b(acc[i][j][t]);
        }
    }
}

// ---------------- scan_apply: prefix over chunks + P = A*S/max(n,1) ---------
#define NCHUNK 64
#define LCHUNK (Tc / NCHUNK)   // 64

__global__ void scan_apply(ushort* __restrict__ AKw, const int* __restrict__ mask,
                           const float* __restrict__ csum, const float* __restrict__ nbuf) {
    const int r = threadIdx.x * 4;
    const int chunk = blockIdx.x, b = blockIdx.y;
    const int row0 = b * Tc + chunk * LCHUNK;
    // exclusive prefix over preceding chunks (csum holds raw per-chunk sums)
    float4 s = {0.f, 0.f, 0.f, 0.f};
    for (int c = 0; c < chunk; ++c) {
        float4 v = *(const float4*)(csum + (((size_t)b * NCHUNK + c) << 10) + r);
        s.x += v.x; s.y += v.y; s.z += v.z; s.w += v.w;
    }
    ushort* p = AKw + (size_t)row0 * 2048 + r;
    for (int t = 0; t < LCHUNK; ++t) {
        const size_t off = (size_t)t * 2048;
        if (mask[row0 + t] != 0) {
            ushort4 kw = *(const ushort4*)(p + off + 1024);
            s.x += b2f(kw.x); s.y += b2f(kw.y); s.z += b2f(kw.z); s.w += b2f(kw.w);
        }
        const float rn = 1.f / fmaxf(nbuf[row0 + t], 1.f);
        ushort4 a = *(const ushort4*)(p + off);
        ushort4 o;
        o.x = f2b(b2f(a.x) * s.x * rn);
        o.y = f2b(b2f(a.y) * s.y * rn);
        o.z = f2b(b2f(a.z) * s.z * rn);
        o.w = f2b(b2f(a.w) * s.w * rn);
        *(ushort4*)(p + off) = o;
    }
}

extern "C" void kernel_launch(void* const* d_in, const int* in_sizes, int n_in,
                              void* d_out, int out_size, void* d_ws, size_t ws_size,
                              hipStream_t stream) {
    const float* x    = (const float*)d_in[0];
    const int*   mask = (const int*)d_in[1];
    const float* W_Q  = (const float*)d_in[2];
    const float* W_K  = (const float*)d_in[3];
    const float* U    = (const float*)d_in[4];
    const float* V    = (const float*)d_in[5];
    const float* Wb   = (const float*)d_in[6];
    const float* bias = (const float*)d_in[7];
    const float* W_O  = (const float*)d_in[8];
    float* out = (float*)d_out;

    char* ws = (char*)d_ws;
    ushort* xb   = (ushort*)ws; ws += (size_t)BT * Dc * 2;            // 67 MB
    ushort* AKw  = (ushort*)ws; ws += (size_t)BT * 2048 * 2;          // 134 MB
    ushort* W1   = (ushort*)ws; ws += (size_t)2048 * Dc * 2;          // 4 MB
    ushort* Mmat = (ushort*)ws; ws += (size_t)Dc * Rc * 2;            // 2 MB
    ushort* Vt   = (ushort*)ws; ws += (size_t)Dc * Rc * 2;
    ushort* Wbt  = (ushort*)ws; ws += (size_t)Dc * Rc * 2;
    ushort* Ut   = (ushort*)ws; ws += (size_t)Dc * Rc * 2;
    ushort* WQt  = (ushort*)ws; ws += (size_t)Dc * Dc * 2;
    ushort* WKt  = (ushort*)ws; ws += (size_t)Dc * Dc * 2;
    ushort* WOb  = (ushort*)ws; ws += (size_t)Dc * Dc * 2;
    float*  csum = (float*)ws;  ws += (size_t)Bc * NCHUNK * Rc * 4;   // 2 MB
    float*  nbuf = (float*)ws;  ws += (size_t)Bc * Tc * 4;
    float*  maskf= (float*)ws;  ws += (size_t)Bc * Tc * 4;
    float*  biasO = (float*)ws; ws += (size_t)Dc * 4;

    // 1. fused prologue: cast x, weight prep, mask scan (one launch)
    fused_prep<<<8200, 256, 0, stream>>>(x, xb, mask, nbuf, maskf,
                                         V, Wb, U, W_Q, W_K, W_O,
                                         Vt, Wbt, Ut, WQt, WKt, WOb);

    // 2. fused weights (batched) + biasO (one launch)
    gemm_bt3b<<<dim3(8, 8, 4), 256, 0, stream>>>(Vt, WQt, Wbt, WKt, WOb, Ut,
                                                 W1, Mmat, W_O, bias, biasO);

    // 3. AKw = xb @ W1^T (M=32768, N=2048, K=1024), bf16 out,
    //    epilogue writes csum raw per-chunk masked column sums
    gemm256<0, 1><<<1024, 512, 0, stream>>>(xb, W1, AKw, nullptr, maskf, csum,
                                            8, Dc, Dc, Dc, 2048);

    // 4. scan_apply: per-block prefix over csum chunks, P = A*S/max(n,1) in place
    scan_apply<<<dim3(NCHUNK, Bc), 256, 0, stream>>>(AKw, mask, csum, nbuf);

    // 5. out = P @ Mmat^T + biasO  (M=32768, N=1024, K=1024), f32 out
    gemm256<1, 0><<<512, 512, 0, stream>>>(AKw, Mmat, out, biasO, nullptr, nullptr,
                                           4, Rc, 2048, Rc, Dc);
}